// Round 15
// baseline (259.068 us; speedup 1.0000x reference)
//
#include <hip/hip_runtime.h>
#include <hip/hip_cooperative_groups.h>

#define NNODE 50000
#define NEDGE 800000
#define NBUCKET 196         // ceil(50000 / 256), bucket = dst >> 8
#define NPB 256             // nodes per bucket
#define CHUNKS 242          // producer chunks
#define CEPB 3306           // ceil(NEDGE / CHUNKS)

typedef __attribute__((ext_vector_type(8))) unsigned short ushort8v;

__device__ inline unsigned short f2bf(float f) {           // round-to-nearest-even
    unsigned int u = __float_as_uint(f);
    u += 0x7FFFu + ((u >> 16) & 1u);
    return (unsigned short)(u >> 16);
}
__device__ inline float bf2f(unsigned short h) {
    return __uint_as_float((unsigned int)h << 16);
}
__device__ inline float bfLO(unsigned int u) { return __uint_as_float(u << 16); }
__device__ inline float bfHI(unsigned int u) { return __uint_as_float(u & 0xFFFF0000u); }

// ========== cooperative CSR build: hist -> scan -> scatter -> fine sort ======
// 242 blocks x 256 threads, ~4KB LDS, tiny VGPR -> co-residency guaranteed.

__global__ __launch_bounds__(256)
void k_csr(const int* __restrict__ src, const int* __restrict__ dst,
           int* __restrict__ hist_g, int* __restrict__ base_g, int* __restrict__ colsum,
           unsigned int* __restrict__ bucketed, int* __restrict__ rowstart,
           unsigned short* __restrict__ csr_src, float* __restrict__ dinv) {
    cooperative_groups::grid_group grid = cooperative_groups::this_grid();
    __shared__ int sA[256];
    __shared__ int sB[256];
    __shared__ int sC[256];
    const int tid = threadIdx.x, bid = blockIdx.x;

    // ---- Phase 1: per-chunk histogram over buckets ----
    {
        const int e0 = bid * CEPB, e1 = min(e0 + CEPB, NEDGE);
        if (tid < NBUCKET) sA[tid] = 0;
        __syncthreads();
        for (int i = e0 + tid; i < e1; i += 256) atomicAdd(&sA[dst[i] >> 8], 1);
        __syncthreads();
        if (tid < NBUCKET) hist_g[tid * 256 + bid] = sA[tid];
    }
    grid.sync();

    // ---- Phase 2: per-bucket exclusive scan over chunks (blocks 0..195) ----
    if (bid < NBUCKET) {
        int v = (tid < CHUNKS) ? hist_g[bid * 256 + tid] : 0;
        sA[tid] = v;
        __syncthreads();
#pragma unroll
        for (int off = 1; off < 256; off <<= 1) {
            int a = (tid >= off) ? sA[tid - off] : 0;
            __syncthreads();
            sA[tid] += a;
            __syncthreads();
        }
        base_g[bid * 256 + tid] = sA[tid] - v;
        if (tid == 255) colsum[bid] = sA[255];
    }
    grid.sync();

    // ---- Phase 3: scatter packed edges to bucket-grouped positions ----
    {
        sA[tid] = (tid < NBUCKET) ? colsum[tid] : 0;
        __syncthreads();
#pragma unroll
        for (int off = 1; off < 256; off <<= 1) {
            int a = (tid >= off) ? sA[tid - off] : 0;
            __syncthreads();
            sA[tid] += a;
            __syncthreads();
        }
        if (tid < NBUCKET) {
            int bb = (tid == 0) ? 0 : sA[tid - 1];      // exclusive bucket base
            sB[tid] = bb + base_g[tid * 256 + bid];      // this chunk's cursor
        }
        __syncthreads();
        const int e0 = bid * CEPB, e1 = min(e0 + CEPB, NEDGE);
        for (int i = e0 + tid; i < e1; i += 256) {
            int d = dst[i], s = src[i];
            int pos = atomicAdd(&sB[d >> 8], 1);
            bucketed[pos] = ((unsigned int)d << 16) | (unsigned int)s;
        }
    }
    grid.sync();

    // ---- Phase 4: per-bucket fine CSR + dinv (blocks 0..195) ----
    if (bid < NBUCKET) {
        sA[tid] = (tid < NBUCKET) ? colsum[tid] : 0;
        __syncthreads();
#pragma unroll
        for (int off = 1; off < 256; off <<= 1) {
            int a = (tid >= off) ? sA[tid - off] : 0;
            __syncthreads();
            sA[tid] += a;
            __syncthreads();
        }
        const int base_out = (bid == 0) ? 0 : sA[bid - 1];
        const int end_out  = sA[bid];
        __syncthreads();
        sB[tid] = 0;
        __syncthreads();
        for (int i = base_out + tid; i < end_out; i += 256)
            atomicAdd(&sB[(bucketed[i] >> 16) & 255], 1);
        __syncthreads();
        int v = sB[tid];
        sC[tid] = v;
        __syncthreads();
#pragma unroll
        for (int off = 1; off < 256; off <<= 1) {
            int a = (tid >= off) ? sC[tid - off] : 0;
            __syncthreads();
            sC[tid] += a;
            __syncthreads();
        }
        int excl = sC[tid] - v;
        int node = (bid << 8) + tid;
        sB[tid] = base_out + excl;           // cursor
        if (node < NNODE) {
            rowstart[node] = base_out + excl;
            dinv[node] = rsqrtf((float)v + 1.0f);
        }
        if (bid == 0 && tid == 0) rowstart[NNODE] = NEDGE;
        __syncthreads();
        for (int i = base_out + tid; i < end_out; i += 256) {
            unsigned int u = bucketed[i];
            int pos = atomicAdd(&sB[(u >> 16) & 255], 1);
            csr_src[pos] = (unsigned short)(u & 0xFFFFu);
        }
    }
}

// ---------------- GEMM + prescale: 64x64 LDS tile, bf16 out, f32/bf16 in ----

template<int FIN, int FOUT, typename XT>
__launch_bounds__(256)
__global__ void k_gemm_prescale(const XT* __restrict__ X, const float* __restrict__ W,
                                const float* __restrict__ dinv, unsigned short* __restrict__ XWs) {
    __shared__ float Xt[FIN * 68];
    __shared__ float Ws[FIN * 64];

    const int tid = threadIdx.x;
    const int r0 = blockIdx.x * 64;

    for (int idx = tid; idx < FIN * 64; idx += 256) {
        int k = idx >> 6, c = idx & 63;
        Ws[idx] = (c < FOUT) ? W[k * FOUT + c] : 0.0f;
    }

    if constexpr (sizeof(XT) == 4) {       // f32 input, float4 chunks
        constexpr int CH = FIN / 4;
        constexpr int CSH = (FIN == 128) ? 5 : 4;
        for (int idx = tid; idx < 64 * CH; idx += 256) {
            int r_lo = idx & 7;
            int c = (idx >> 3) & (CH - 1);
            int r = ((idx >> (3 + CSH)) << 3) + r_lo;
            int rr = r0 + r; if (rr >= NNODE) rr = NNODE - 1;
            float4 v = *(const float4*)((const float*)X + (size_t)rr * FIN + c * 4);
            Xt[(4 * c + 0) * 68 + r] = v.x;
            Xt[(4 * c + 1) * 68 + r] = v.y;
            Xt[(4 * c + 2) * 68 + r] = v.z;
            Xt[(4 * c + 3) * 68 + r] = v.w;
        }
    } else {                               // bf16 input, ushort8 chunks
        constexpr int CH = FIN / 8;
        constexpr int CSH = (FIN == 128) ? 4 : 3;
        for (int idx = tid; idx < 64 * CH; idx += 256) {
            int r_lo = idx & 7;
            int c = (idx >> 3) & (CH - 1);
            int r = ((idx >> (3 + CSH)) << 3) + r_lo;
            int rr = r0 + r; if (rr >= NNODE) rr = NNODE - 1;
            ushort8v v = *(const ushort8v*)((const unsigned short*)X + (size_t)rr * FIN + c * 8);
#pragma unroll
            for (int t = 0; t < 8; ++t)
                Xt[(8 * c + t) * 68 + r] = bf2f(v[t]);
        }
    }
    __syncthreads();

    const int cg = tid & 15;    // col group
    const int rg = tid >> 4;    // row group

    float acc[4][4] = {};
#pragma unroll 4
    for (int k = 0; k < FIN; ++k) {
        float4 xv = *(const float4*)&Xt[k * 68 + 4 * rg];
        float4 wv = *(const float4*)&Ws[k * 64 + 4 * cg];
#pragma unroll
        for (int i = 0; i < 4; ++i) {
            float xi = (i == 0) ? xv.x : (i == 1) ? xv.y : (i == 2) ? xv.z : xv.w;
            acc[i][0] = fmaf(xi, wv.x, acc[i][0]);
            acc[i][1] = fmaf(xi, wv.y, acc[i][1]);
            acc[i][2] = fmaf(xi, wv.z, acc[i][2]);
            acc[i][3] = fmaf(xi, wv.w, acc[i][3]);
        }
    }

    if (4 * cg + 4 <= FOUT) {
#pragma unroll
        for (int i = 0; i < 4; ++i) {
            int row = r0 + 4 * rg + i;
            if (row < NNODE) {
                float dv = dinv[row];
                ushort4 o = { f2bf(acc[i][0] * dv), f2bf(acc[i][1] * dv),
                              f2bf(acc[i][2] * dv), f2bf(acc[i][3] * dv) };
                *(ushort4*)(XWs + (size_t)row * FOUT + 4 * cg) = o;
            }
        }
    }
}

// ---------------- CSR aggregate + finalize: uint4 bf16 unpack ---------------
// wave per node; lane = g*8+q (g = edge group 0..7, q = feature octet).

template<int F, bool RELU, bool OUTBF>
__launch_bounds__(256)
__global__ void k_aggregate(const unsigned short* __restrict__ XWs, const int* __restrict__ rowstart,
                            const unsigned short* __restrict__ csr_src, const float* __restrict__ dinv,
                            const float* __restrict__ b, void* __restrict__ outp) {
    constexpr int NQ = F / 8;
    const int wid  = threadIdx.x >> 6;
    const int lane = threadIdx.x & 63;
    const int g = lane >> 3;
    const int q = lane & 7;
    const int d = blockIdx.x * 4 + wid;
    if (d >= NNODE) return;

    const int beg = rowstart[d];
    const int end = rowstart[d + 1];
    const bool qa = (q < NQ);

    float acc[8] = {};

    for (int base = beg; base < end; base += 64) {
        int idx = base + lane;
        int sv = (idx < end) ? (int)csr_src[idx] : 0;
        int nv = min(64, end - base);
        for (int j = 0; j < nv; j += 8) {
            int jj = j + g;
            int s = __shfl(sv, jj);
            if (jj < nv && qa) {
                uint4 v = *(const uint4*)(XWs + (size_t)s * F + 8 * q);
                acc[0] += bfLO(v.x); acc[1] += bfHI(v.x);
                acc[2] += bfLO(v.y); acc[3] += bfHI(v.y);
                acc[4] += bfLO(v.z); acc[5] += bfHI(v.z);
                acc[6] += bfLO(v.w); acc[7] += bfHI(v.w);
            }
        }
    }

#pragma unroll
    for (int mask = 8; mask <= 32; mask <<= 1) {
#pragma unroll
        for (int t = 0; t < 8; ++t) acc[t] += __shfl_xor(acc[t], mask);
    }

    if (g == 0 && qa) {
        uint4 sv4 = *(const uint4*)(XWs + (size_t)d * F + 8 * q);
        float self[8] = { bfLO(sv4.x), bfHI(sv4.x), bfLO(sv4.y), bfHI(sv4.y),
                          bfLO(sv4.z), bfHI(sv4.z), bfLO(sv4.w), bfHI(sv4.w) };
        float dv = dinv[d];
        float o[8];
#pragma unroll
        for (int t = 0; t < 8; ++t) {
            o[t] = fmaf(acc[t] + self[t], dv, b[8 * q + t]);
            if (RELU) o[t] = fmaxf(o[t], 0.f);
        }
        if (OUTBF) {
            ushort8v ov;
#pragma unroll
            for (int t = 0; t < 8; ++t) ov[t] = f2bf(o[t]);
            *(ushort8v*)((unsigned short*)outp + (size_t)d * F + 8 * q) = ov;
        } else {
            float4 o0 = { o[0], o[1], o[2], o[3] };
            float4 o1 = { o[4], o[5], o[6], o[7] };
            *(float4*)((float*)outp + (size_t)d * F + 8 * q)     = o0;
            *(float4*)((float*)outp + (size_t)d * F + 8 * q + 4) = o1;
        }
    }
}

extern "C" void kernel_launch(void* const* d_in, const int* in_sizes, int n_in,
                              void* d_out, int out_size, void* d_ws, size_t ws_size,
                              hipStream_t stream) {
    const float* x  = (const float*)d_in[0];
    const int*   ei = (const int*)d_in[1];
    const float* W1 = (const float*)d_in[2];
    const float* b1 = (const float*)d_in[3];
    const float* W2 = (const float*)d_in[4];
    const float* b2 = (const float*)d_in[5];
    const float* W3 = (const float*)d_in[6];
    const float* b3 = (const float*)d_in[7];
    float* out = (float*)d_out;

    const int* src = ei;
    const int* dst = ei + NEDGE;

    char* p = (char*)d_ws;
    auto alloc = [&](size_t bytes) { char* r = p; p += (bytes + 255) & ~size_t(255); return r; };
    unsigned int* bucketed = (unsigned int*)alloc((size_t)NEDGE * 4);
    int*   hist_g     = (int*)  alloc(NBUCKET * 256 * 4);
    int*   base_g     = (int*)  alloc(NBUCKET * 256 * 4);
    int*   colsum     = (int*)  alloc(NBUCKET * 4);
    int*   rowstart   = (int*)  alloc((NNODE + 1) * 4);
    unsigned short* csr_src = (unsigned short*)alloc((size_t)NEDGE * 2);
    float* dinvp      = (float*)alloc(NNODE * 4);
    unsigned short* XWs = (unsigned short*)alloc((size_t)NNODE * 64 * 2 + 256);
    unsigned short* H1  = (unsigned short*)alloc((size_t)NNODE * 64 * 2 + 256);
    unsigned short* H2  = (unsigned short*)alloc((size_t)NNODE * 64 * 2 + 256);

    const int B = 256;
    const int gGemm = (NNODE + 63) / 64;          // 782
    const int gAgg  = (NNODE + 3) / 4;            // 12500

    // CSR build: single cooperative kernel (242 blocks, 4KB LDS -> safe occupancy)
    void* args[] = { (void*)&src, (void*)&dst, (void*)&hist_g, (void*)&base_g,
                     (void*)&colsum, (void*)&bucketed, (void*)&rowstart,
                     (void*)&csr_src, (void*)&dinvp };
    hipLaunchCooperativeKernel((const void*)k_csr, dim3(CHUNKS), dim3(B), args, 0, stream);

    // layer 1: 128 -> 64, relu (f32 input)
    k_gemm_prescale<128, 64, float><<<gGemm, B, 0, stream>>>(x, W1, dinvp, XWs);
    k_aggregate<64, true, true><<<gAgg, B, 0, stream>>>(XWs, rowstart, csr_src, dinvp, b1, H1);

    // layer 2: 64 -> 64, relu (bf16 input)
    k_gemm_prescale<64, 64, unsigned short><<<gGemm, B, 0, stream>>>(H1, W2, dinvp, XWs);
    k_aggregate<64, true, true><<<gAgg, B, 0, stream>>>(XWs, rowstart, csr_src, dinvp, b2, H2);

    // layer 3: 64 -> 40, no act (bf16 input, f32 output)
    k_gemm_prescale<64, 40, unsigned short><<<gGemm, B, 0, stream>>>(H2, W3, dinvp, XWs);
    k_aggregate<40, false, false><<<gAgg, B, 0, stream>>>(XWs, rowstart, csr_src, dinvp, b3, out);
}

// Round 16
// 179.187 us; speedup vs baseline: 1.4458x; 1.4458x over previous
//
#include <hip/hip_runtime.h>

#define NNODE 50000
#define NEDGE 800000
#define NBUCKET 196         // ceil(50000 / 256), bucket = dst >> 8
#define NPB 256             // nodes per bucket
#define EPB 3125            // NEDGE / 256 edges per producer block

typedef __attribute__((ext_vector_type(8))) unsigned short ushort8v;

__device__ inline unsigned short f2bf(float f) {           // round-to-nearest-even
    unsigned int u = __float_as_uint(f);
    u += 0x7FFFu + ((u >> 16) & 1u);
    return (unsigned short)(u >> 16);
}
__device__ inline float bf2f(unsigned short h) {
    return __uint_as_float((unsigned int)h << 16);
}
__device__ inline float bfLO(unsigned int u) { return __uint_as_float(u << 16); }
__device__ inline float bfHI(unsigned int u) { return __uint_as_float(u & 0xFFFF0000u); }

// ---------------- CSR build (R13-proven 4-kernel chain) ----------------

__global__ __launch_bounds__(256) void k_histA(const int* __restrict__ dst, int* __restrict__ hist_g) {
    __shared__ int h[NBUCKET];
    const int tid = threadIdx.x, pb = blockIdx.x, e0 = pb * EPB;
    if (tid < NBUCKET) h[tid] = 0;
    __syncthreads();
    for (int i = tid; i < EPB; i += 256)
        atomicAdd(&h[dst[e0 + i] >> 8], 1);
    __syncthreads();
    if (tid < NBUCKET) hist_g[tid * 256 + pb] = h[tid];
}

__global__ __launch_bounds__(256) void k_scanA1(const int* __restrict__ hist_g, int* __restrict__ base_g,
                                                int* __restrict__ colsum) {
    __shared__ int s[256];
    const int b = blockIdx.x, t = threadIdx.x;
    int v = hist_g[b * 256 + t];
    s[t] = v;
    __syncthreads();
#pragma unroll
    for (int off = 1; off < 256; off <<= 1) {
        int a = (t >= off) ? s[t - off] : 0;
        __syncthreads();
        s[t] += a;
        __syncthreads();
    }
    base_g[b * 256 + t] = s[t] - v;           // exclusive
    if (t == 255) colsum[b] = s[t];
}

__device__ inline void scan_colsum(const int* __restrict__ colsum, int* cs, int tid) {
    cs[tid] = (tid < NBUCKET) ? colsum[tid] : 0;
    __syncthreads();
#pragma unroll
    for (int off = 1; off < 256; off <<= 1) {
        int a = (tid >= off) ? cs[tid - off] : 0;
        __syncthreads();
        cs[tid] += a;
        __syncthreads();
    }
}

__global__ __launch_bounds__(256) void k_scatterA(const int* __restrict__ src, const int* __restrict__ dst,
                          const int* __restrict__ base_g, const int* __restrict__ colsum,
                          unsigned int* __restrict__ bucketed) {
    __shared__ int cs[256];
    __shared__ int cur[NBUCKET];
    const int tid = threadIdx.x, pb = blockIdx.x, e0 = pb * EPB;
    scan_colsum(colsum, cs, tid);
    if (tid < NBUCKET) {
        int bb = (tid == 0) ? 0 : cs[tid - 1];
        cur[tid] = bb + base_g[tid * 256 + pb];
    }
    __syncthreads();
    for (int i = tid; i < EPB; i += 256) {
        int d = dst[e0 + i], s = src[e0 + i];
        int pos = atomicAdd(&cur[d >> 8], 1);
        bucketed[pos] = ((unsigned int)d << 16) | (unsigned int)s;
    }
}

__global__ __launch_bounds__(256) void k_bucketB2(const unsigned int* __restrict__ bucketed,
                          const int* __restrict__ colsum, int* __restrict__ rowstart,
                          unsigned short* __restrict__ csr_src, float* __restrict__ dinv) {
    __shared__ int cs[256];
    __shared__ int cnt[NPB];
    __shared__ int ex[NPB];
    __shared__ int cur[NPB];
    const int tid = threadIdx.x, b = blockIdx.x;
    scan_colsum(colsum, cs, tid);
    const int base_out = (b == 0) ? 0 : cs[b - 1];
    const int end_out  = cs[b];

    cnt[tid] = 0;
    __syncthreads();
    for (int i = base_out + tid; i < end_out; i += 256)
        atomicAdd(&cnt[(bucketed[i] >> 16) & 255], 1);
    __syncthreads();

    int v = cnt[tid];
    ex[tid] = v;
    __syncthreads();
#pragma unroll
    for (int off = 1; off < 256; off <<= 1) {
        int a = (tid >= off) ? ex[tid - off] : 0;
        __syncthreads();
        ex[tid] += a;
        __syncthreads();
    }
    int excl = ex[tid] - v;
    int node = (b << 8) + tid;
    cur[tid] = base_out + excl;
    if (node < NNODE) {
        rowstart[node] = base_out + excl;
        dinv[node] = rsqrtf((float)v + 1.0f);
    }
    if (b == 0 && tid == 0) rowstart[NNODE] = NEDGE;
    __syncthreads();

    for (int i = base_out + tid; i < end_out; i += 256) {
        unsigned int u = bucketed[i];
        int pos = atomicAdd(&cur[(u >> 16) & 255], 1);
        csr_src[pos] = (unsigned short)(u & 0xFFFFu);
    }
}

// ---------------- GEMM1 + prescale: f32 in, bf16 out (R13-proven) ----------

template<int FIN, int FOUT>
__launch_bounds__(256)
__global__ void k_gemm_prescale(const float* __restrict__ X, const float* __restrict__ W,
                                const float* __restrict__ dinv, unsigned short* __restrict__ XWs) {
    __shared__ float Xt[FIN * 68];
    __shared__ float Ws[FIN * 64];

    const int tid = threadIdx.x;
    const int r0 = blockIdx.x * 64;

    for (int idx = tid; idx < FIN * 64; idx += 256) {
        int k = idx >> 6, c = idx & 63;
        Ws[idx] = (c < FOUT) ? W[k * FOUT + c] : 0.0f;
    }

    constexpr int CH = FIN / 4;
    constexpr int CSH = (FIN == 128) ? 5 : 4;
    for (int idx = tid; idx < 64 * CH; idx += 256) {
        int r_lo = idx & 7;
        int c = (idx >> 3) & (CH - 1);
        int r = ((idx >> (3 + CSH)) << 3) + r_lo;
        int rr = r0 + r; if (rr >= NNODE) rr = NNODE - 1;
        float4 v = *(const float4*)(X + (size_t)rr * FIN + c * 4);
        Xt[(4 * c + 0) * 68 + r] = v.x;
        Xt[(4 * c + 1) * 68 + r] = v.y;
        Xt[(4 * c + 2) * 68 + r] = v.z;
        Xt[(4 * c + 3) * 68 + r] = v.w;
    }
    __syncthreads();

    const int cg = tid & 15;
    const int rg = tid >> 4;

    float acc[4][4] = {};
#pragma unroll 4
    for (int k = 0; k < FIN; ++k) {
        float4 xv = *(const float4*)&Xt[k * 68 + 4 * rg];
        float4 wv = *(const float4*)&Ws[k * 64 + 4 * cg];
#pragma unroll
        for (int i = 0; i < 4; ++i) {
            float xi = (i == 0) ? xv.x : (i == 1) ? xv.y : (i == 2) ? xv.z : xv.w;
            acc[i][0] = fmaf(xi, wv.x, acc[i][0]);
            acc[i][1] = fmaf(xi, wv.y, acc[i][1]);
            acc[i][2] = fmaf(xi, wv.z, acc[i][2]);
            acc[i][3] = fmaf(xi, wv.w, acc[i][3]);
        }
    }

    if (4 * cg + 4 <= FOUT) {
#pragma unroll
        for (int i = 0; i < 4; ++i) {
            int row = r0 + 4 * rg + i;
            if (row < NNODE) {
                float dv = dinv[row];
                ushort4 o = { f2bf(acc[i][0] * dv), f2bf(acc[i][1] * dv),
                              f2bf(acc[i][2] * dv), f2bf(acc[i][3] * dv) };
                *(ushort4*)(XWs + (size_t)row * FOUT + 4 * cg) = o;
            }
        }
    }
}

// ------------- FUSED aggregate + next-layer GEMM (layers 1->2, 2->3) -------
// Block owns 64 dst nodes. Phase A: 4 waves aggregate 16 nodes each
// (gather XWin rows, reduce, +bias, ReLU) writing TRANSPOSED into Xt LDS.
// Phase B: 64x64(xFOUT) GEMM from LDS, prescale dinv, bf16 store to XWout.

template<int FOUT>
__launch_bounds__(256)
__global__ void k_agg_gemm(const unsigned short* __restrict__ XWin, const int* __restrict__ rowstart,
                           const unsigned short* __restrict__ csr_src, const float* __restrict__ dinv,
                           const float* __restrict__ bias, const float* __restrict__ W,
                           unsigned short* __restrict__ XWout) {
    __shared__ float Xt[64 * 68];   // aggregated H, transposed [feat][row]
    __shared__ float Ws[64 * 64];

    const int tid = threadIdx.x;
    const int wid = tid >> 6, lane = tid & 63;
    const int g = lane >> 3, q = lane & 7;
    const int r0 = blockIdx.x * 64;

    // stage W (zero-pad cols >= FOUT)
    for (int idx = tid; idx < 64 * 64; idx += 256) {
        int k = idx >> 6, c = idx & 63;
        Ws[idx] = (c < FOUT) ? W[k * FOUT + c] : 0.0f;
    }

    float bb[8];
#pragma unroll
    for (int t = 0; t < 8; ++t) bb[t] = bias[8 * q + t];

    // Phase A: aggregate 16 nodes per wave
    for (int n = 0; n < 16; ++n) {
        const int rr = wid * 16 + n;
        const int d = r0 + rr;
        if (d < NNODE) {
            const int beg = rowstart[d];
            const int end = rowstart[d + 1];
            float acc[8] = {};
            for (int base = beg; base < end; base += 64) {
                int idx = base + lane;
                int sv = (idx < end) ? (int)csr_src[idx] : 0;
                int nv = min(64, end - base);
                for (int j = 0; j < nv; j += 8) {
                    int jj = j + g;
                    int s = __shfl(sv, jj);
                    if (jj < nv) {
                        uint4 v = *(const uint4*)(XWin + (size_t)s * 64 + 8 * q);
                        acc[0] += bfLO(v.x); acc[1] += bfHI(v.x);
                        acc[2] += bfLO(v.y); acc[3] += bfHI(v.y);
                        acc[4] += bfLO(v.z); acc[5] += bfHI(v.z);
                        acc[6] += bfLO(v.w); acc[7] += bfHI(v.w);
                    }
                }
            }
#pragma unroll
            for (int mask = 8; mask <= 32; mask <<= 1) {
#pragma unroll
                for (int t = 0; t < 8; ++t) acc[t] += __shfl_xor(acc[t], mask);
            }
            if (g == 0) {
                uint4 sv4 = *(const uint4*)(XWin + (size_t)d * 64 + 8 * q);
                float self[8] = { bfLO(sv4.x), bfHI(sv4.x), bfLO(sv4.y), bfHI(sv4.y),
                                  bfLO(sv4.z), bfHI(sv4.z), bfLO(sv4.w), bfHI(sv4.w) };
                float dv = dinv[d];
#pragma unroll
                for (int t = 0; t < 8; ++t) {
                    float o = fmaf(acc[t] + self[t], dv, bb[t]);
                    Xt[(8 * q + t) * 68 + rr] = fmaxf(o, 0.0f);   // ReLU (layers 1,2)
                }
            }
        } else if (g == 0) {
#pragma unroll
            for (int t = 0; t < 8; ++t) Xt[(8 * q + t) * 68 + rr] = 0.0f;
        }
    }
    __syncthreads();

    // Phase B: 64-wide GEMM from LDS
    const int cg = tid & 15;
    const int rg = tid >> 4;

    float acc[4][4] = {};
#pragma unroll 4
    for (int k = 0; k < 64; ++k) {
        float4 xv = *(const float4*)&Xt[k * 68 + 4 * rg];
        float4 wv = *(const float4*)&Ws[k * 64 + 4 * cg];
#pragma unroll
        for (int i = 0; i < 4; ++i) {
            float xi = (i == 0) ? xv.x : (i == 1) ? xv.y : (i == 2) ? xv.z : xv.w;
            acc[i][0] = fmaf(xi, wv.x, acc[i][0]);
            acc[i][1] = fmaf(xi, wv.y, acc[i][1]);
            acc[i][2] = fmaf(xi, wv.z, acc[i][2]);
            acc[i][3] = fmaf(xi, wv.w, acc[i][3]);
        }
    }

    if (4 * cg + 4 <= FOUT) {
#pragma unroll
        for (int i = 0; i < 4; ++i) {
            int row = r0 + 4 * rg + i;
            if (row < NNODE) {
                float dv = dinv[row];
                ushort4 o = { f2bf(acc[i][0] * dv), f2bf(acc[i][1] * dv),
                              f2bf(acc[i][2] * dv), f2bf(acc[i][3] * dv) };
                *(ushort4*)(XWout + (size_t)row * FOUT + 4 * cg) = o;
            }
        }
    }
}

// ---------------- final CSR aggregate (F=40, f32 out) ----------------------

template<int F, bool RELU>
__launch_bounds__(256)
__global__ void k_aggregate(const unsigned short* __restrict__ XWs, const int* __restrict__ rowstart,
                            const unsigned short* __restrict__ csr_src, const float* __restrict__ dinv,
                            const float* __restrict__ b, float* __restrict__ out) {
    constexpr int NQ = F / 8;
    const int wid  = threadIdx.x >> 6;
    const int lane = threadIdx.x & 63;
    const int g = lane >> 3;
    const int q = lane & 7;
    const int d = blockIdx.x * 4 + wid;
    if (d >= NNODE) return;

    const int beg = rowstart[d];
    const int end = rowstart[d + 1];
    const bool qa = (q < NQ);

    float acc[8] = {};

    for (int base = beg; base < end; base += 64) {
        int idx = base + lane;
        int sv = (idx < end) ? (int)csr_src[idx] : 0;
        int nv = min(64, end - base);
        for (int j = 0; j < nv; j += 8) {
            int jj = j + g;
            int s = __shfl(sv, jj);
            if (jj < nv && qa) {
                uint4 v = *(const uint4*)(XWs + (size_t)s * F + 8 * q);
                acc[0] += bfLO(v.x); acc[1] += bfHI(v.x);
                acc[2] += bfLO(v.y); acc[3] += bfHI(v.y);
                acc[4] += bfLO(v.z); acc[5] += bfHI(v.z);
                acc[6] += bfLO(v.w); acc[7] += bfHI(v.w);
            }
        }
    }

#pragma unroll
    for (int mask = 8; mask <= 32; mask <<= 1) {
#pragma unroll
        for (int t = 0; t < 8; ++t) acc[t] += __shfl_xor(acc[t], mask);
    }

    if (g == 0 && qa) {
        uint4 sv4 = *(const uint4*)(XWs + (size_t)d * F + 8 * q);
        float self[8] = { bfLO(sv4.x), bfHI(sv4.x), bfLO(sv4.y), bfHI(sv4.y),
                          bfLO(sv4.z), bfHI(sv4.z), bfLO(sv4.w), bfHI(sv4.w) };
        float dv = dinv[d];
        float o[8];
#pragma unroll
        for (int t = 0; t < 8; ++t) {
            o[t] = fmaf(acc[t] + self[t], dv, b[8 * q + t]);
            if (RELU) o[t] = fmaxf(o[t], 0.f);
        }
        float4 o0 = { o[0], o[1], o[2], o[3] };
        float4 o1 = { o[4], o[5], o[6], o[7] };
        *(float4*)(out + (size_t)d * F + 8 * q)     = o0;
        *(float4*)(out + (size_t)d * F + 8 * q + 4) = o1;
    }
}

extern "C" void kernel_launch(void* const* d_in, const int* in_sizes, int n_in,
                              void* d_out, int out_size, void* d_ws, size_t ws_size,
                              hipStream_t stream) {
    const float* x  = (const float*)d_in[0];
    const int*   ei = (const int*)d_in[1];
    const float* W1 = (const float*)d_in[2];
    const float* b1 = (const float*)d_in[3];
    const float* W2 = (const float*)d_in[4];
    const float* b2 = (const float*)d_in[5];
    const float* W3 = (const float*)d_in[6];
    const float* b3 = (const float*)d_in[7];
    float* out = (float*)d_out;

    const int* src = ei;
    const int* dst = ei + NEDGE;

    char* p = (char*)d_ws;
    auto alloc = [&](size_t bytes) { char* r = p; p += (bytes + 255) & ~size_t(255); return r; };
    unsigned int* bucketed = (unsigned int*)alloc((size_t)NEDGE * 4);
    int*   hist_g     = (int*)  alloc(NBUCKET * 256 * 4);
    int*   base_g     = (int*)  alloc(NBUCKET * 256 * 4);
    int*   colsum     = (int*)  alloc(NBUCKET * 4);
    int*   rowstart   = (int*)  alloc((NNODE + 1) * 4);
    unsigned short* csr_src = (unsigned short*)alloc((size_t)NEDGE * 2);
    float* dinvp      = (float*)alloc(NNODE * 4);
    unsigned short* XWsA = (unsigned short*)alloc((size_t)NNODE * 64 * 2 + 256);
    unsigned short* XWsB = (unsigned short*)alloc((size_t)NNODE * 64 * 2 + 256);
    unsigned short* XWsC = (unsigned short*)alloc((size_t)NNODE * 40 * 2 + 256);

    const int B = 256;
    const int gGemm = (NNODE + 63) / 64;          // 782
    const int gAgg  = (NNODE + 3) / 4;            // 12500

    // CSR build + norm (R13 chain)
    k_histA   <<<256, B, 0, stream>>>(dst, hist_g);
    k_scanA1  <<<NBUCKET, B, 0, stream>>>(hist_g, base_g, colsum);
    k_scatterA<<<256, B, 0, stream>>>(src, dst, base_g, colsum, bucketed);
    k_bucketB2<<<NBUCKET, B, 0, stream>>>(bucketed, colsum, rowstart, csr_src, dinvp);

    // layer 1 GEMM: x (f32) -> XWsA (bf16, prescaled)
    k_gemm_prescale<128, 64><<<gGemm, B, 0, stream>>>(x, W1, dinvp, XWsA);

    // fused: aggregate(XWsA)+b1+ReLU -> xW2, prescale -> XWsB
    k_agg_gemm<64><<<gGemm, B, 0, stream>>>(XWsA, rowstart, csr_src, dinvp, b1, W2, XWsB);

    // fused: aggregate(XWsB)+b2+ReLU -> xW3, prescale -> XWsC
    k_agg_gemm<40><<<gGemm, B, 0, stream>>>(XWsB, rowstart, csr_src, dinvp, b2, W3, XWsC);

    // final aggregate: XWsC + b3 -> out (f32)
    k_aggregate<40, false><<<gAgg, B, 0, stream>>>(XWsC, rowstart, csr_src, dinvp, b3, out);
}

// Round 17
// 150.408 us; speedup vs baseline: 1.7224x; 1.1913x over previous
//
#include <hip/hip_runtime.h>

#define NNODE 50000
#define NEDGE 800000
#define NBUCKET 196         // ceil(50000 / 256), bucket = dst >> 8
#define NPB 256             // nodes per bucket
#define EPB 3125            // NEDGE / 256 edges per producer block
#define G1BLK 782           // ceil(50000/64) GEMM1 tiles

typedef __attribute__((ext_vector_type(8))) unsigned short ushort8v;

__device__ inline unsigned short f2bf(float f) {           // round-to-nearest-even
    unsigned int u = __float_as_uint(f);
    u += 0x7FFFu + ((u >> 16) & 1u);
    return (unsigned short)(u >> 16);
}
__device__ inline float bf2f(unsigned short h) {
    return __uint_as_float((unsigned int)h << 16);
}
__device__ inline float bfLO(unsigned int u) { return __uint_as_float(u << 16); }
__device__ inline float bfHI(unsigned int u) { return __uint_as_float(u & 0xFFFF0000u); }

// ========== merged: edge histogram (blocks 0..255) ∥ GEMM1 (256..1037) =====
// Fully independent (GEMM1 writes RAW XW, no dinv dependency).

__global__ __launch_bounds__(256)
void k_hist_gemm1(const int* __restrict__ dst, int* __restrict__ hist_g,
                  const float* __restrict__ x, const float* __restrict__ W1,
                  unsigned short* __restrict__ XWs) {
    __shared__ float Xt[128 * 68];
    __shared__ float Ws[128 * 64];
    __shared__ int h[NBUCKET];
    const int tid = threadIdx.x, bid = blockIdx.x;

    if (bid < 256) {                      // ---- histogram chunk ----
        const int e0 = bid * EPB;
        if (tid < NBUCKET) h[tid] = 0;
        __syncthreads();
        for (int i = tid; i < EPB; i += 256)
            atomicAdd(&h[dst[e0 + i] >> 8], 1);
        __syncthreads();
        if (tid < NBUCKET) hist_g[tid * 256 + bid] = h[tid];
        return;
    }

    // ---- GEMM1 tile: 64 rows x 64 cols, FIN=128, RAW output ----
    const int r0 = (bid - 256) * 64;

    for (int idx = tid; idx < 128 * 64; idx += 256)
        Ws[idx] = W1[idx];

    for (int idx = tid; idx < 64 * 32; idx += 256) {
        int r_lo = idx & 7;
        int c = (idx >> 3) & 31;
        int r = ((idx >> 8) << 3) + r_lo;
        int rr = r0 + r; if (rr >= NNODE) rr = NNODE - 1;
        float4 v = *(const float4*)(x + (size_t)rr * 128 + c * 4);
        Xt[(4 * c + 0) * 68 + r] = v.x;
        Xt[(4 * c + 1) * 68 + r] = v.y;
        Xt[(4 * c + 2) * 68 + r] = v.z;
        Xt[(4 * c + 3) * 68 + r] = v.w;
    }
    __syncthreads();

    const int cg = tid & 15;
    const int rg = tid >> 4;

    float acc[4][4] = {};
#pragma unroll 4
    for (int k = 0; k < 128; ++k) {
        float4 xv = *(const float4*)&Xt[k * 68 + 4 * rg];
        float4 wv = *(const float4*)&Ws[k * 64 + 4 * cg];
#pragma unroll
        for (int i = 0; i < 4; ++i) {
            float xi = (i == 0) ? xv.x : (i == 1) ? xv.y : (i == 2) ? xv.z : xv.w;
            acc[i][0] = fmaf(xi, wv.x, acc[i][0]);
            acc[i][1] = fmaf(xi, wv.y, acc[i][1]);
            acc[i][2] = fmaf(xi, wv.z, acc[i][2]);
            acc[i][3] = fmaf(xi, wv.w, acc[i][3]);
        }
    }

#pragma unroll
    for (int i = 0; i < 4; ++i) {
        int row = r0 + 4 * rg + i;
        if (row < NNODE) {
            ushort4 o = { f2bf(acc[i][0]), f2bf(acc[i][1]), f2bf(acc[i][2]), f2bf(acc[i][3]) };
            *(ushort4*)(XWs + (size_t)row * 64 + 4 * cg) = o;
        }
    }
}

// ---------------- CSR build rest (R13-proven) ----------------

__global__ __launch_bounds__(256) void k_scanA1(const int* __restrict__ hist_g, int* __restrict__ base_g,
                                                int* __restrict__ colsum) {
    __shared__ int s[256];
    const int b = blockIdx.x, t = threadIdx.x;
    int v = hist_g[b * 256 + t];
    s[t] = v;
    __syncthreads();
#pragma unroll
    for (int off = 1; off < 256; off <<= 1) {
        int a = (t >= off) ? s[t - off] : 0;
        __syncthreads();
        s[t] += a;
        __syncthreads();
    }
    base_g[b * 256 + t] = s[t] - v;           // exclusive
    if (t == 255) colsum[b] = s[t];
}

__device__ inline void scan_colsum(const int* __restrict__ colsum, int* cs, int tid) {
    cs[tid] = (tid < NBUCKET) ? colsum[tid] : 0;
    __syncthreads();
#pragma unroll
    for (int off = 1; off < 256; off <<= 1) {
        int a = (tid >= off) ? cs[tid - off] : 0;
        __syncthreads();
        cs[tid] += a;
        __syncthreads();
    }
}

__global__ __launch_bounds__(256) void k_scatterA(const int* __restrict__ src, const int* __restrict__ dst,
                          const int* __restrict__ base_g, const int* __restrict__ colsum,
                          unsigned int* __restrict__ bucketed) {
    __shared__ int cs[256];
    __shared__ int cur[NBUCKET];
    const int tid = threadIdx.x, pb = blockIdx.x, e0 = pb * EPB;
    scan_colsum(colsum, cs, tid);
    if (tid < NBUCKET) {
        int bb = (tid == 0) ? 0 : cs[tid - 1];
        cur[tid] = bb + base_g[tid * 256 + pb];
    }
    __syncthreads();
    for (int i = tid; i < EPB; i += 256) {
        int d = dst[e0 + i], s = src[e0 + i];
        int pos = atomicAdd(&cur[d >> 8], 1);
        bucketed[pos] = ((unsigned int)d << 16) | (unsigned int)s;
    }
}

__global__ __launch_bounds__(256) void k_bucketB2(const unsigned int* __restrict__ bucketed,
                          const int* __restrict__ colsum, int* __restrict__ rowstart,
                          unsigned short* __restrict__ csr_src, float* __restrict__ dinv) {
    __shared__ int cs[256];
    __shared__ int cnt[NPB];
    __shared__ int ex[NPB];
    __shared__ int cur[NPB];
    const int tid = threadIdx.x, b = blockIdx.x;
    scan_colsum(colsum, cs, tid);
    const int base_out = (b == 0) ? 0 : cs[b - 1];
    const int end_out  = cs[b];

    cnt[tid] = 0;
    __syncthreads();
    for (int i = base_out + tid; i < end_out; i += 256)
        atomicAdd(&cnt[(bucketed[i] >> 16) & 255], 1);
    __syncthreads();

    int v = cnt[tid];
    ex[tid] = v;
    __syncthreads();
#pragma unroll
    for (int off = 1; off < 256; off <<= 1) {
        int a = (tid >= off) ? ex[tid - off] : 0;
        __syncthreads();
        ex[tid] += a;
        __syncthreads();
    }
    int excl = ex[tid] - v;
    int node = (b << 8) + tid;
    cur[tid] = base_out + excl;
    if (node < NNODE) {
        rowstart[node] = base_out + excl;
        dinv[node] = rsqrtf((float)v + 1.0f);
    }
    if (b == 0 && tid == 0) rowstart[NNODE] = NEDGE;
    __syncthreads();

    for (int i = base_out + tid; i < end_out; i += 256) {
        unsigned int u = bucketed[i];
        int pos = atomicAdd(&cur[(u >> 16) & 255], 1);
        csr_src[pos] = (unsigned short)(u & 0xFFFFu);
    }
}

// ---------------- GEMM + prescale (layers 2,3): bf16 in, bf16 out ----------

template<int FIN, int FOUT>
__launch_bounds__(256)
__global__ void k_gemm_prescale(const unsigned short* __restrict__ X, const float* __restrict__ W,
                                const float* __restrict__ dinv, unsigned short* __restrict__ XWs) {
    __shared__ float Xt[FIN * 68];
    __shared__ float Ws[FIN * 64];

    const int tid = threadIdx.x;
    const int r0 = blockIdx.x * 64;

    for (int idx = tid; idx < FIN * 64; idx += 256) {
        int k = idx >> 6, c = idx & 63;
        Ws[idx] = (c < FOUT) ? W[k * FOUT + c] : 0.0f;
    }

    constexpr int CH = FIN / 8;
    constexpr int CSH = (FIN == 128) ? 4 : 3;
    for (int idx = tid; idx < 64 * CH; idx += 256) {
        int r_lo = idx & 7;
        int c = (idx >> 3) & (CH - 1);
        int r = ((idx >> (3 + CSH)) << 3) + r_lo;
        int rr = r0 + r; if (rr >= NNODE) rr = NNODE - 1;
        ushort8v v = *(const ushort8v*)(X + (size_t)rr * FIN + c * 8);
#pragma unroll
        for (int t = 0; t < 8; ++t)
            Xt[(8 * c + t) * 68 + r] = bf2f(v[t]);
    }
    __syncthreads();

    const int cg = tid & 15;
    const int rg = tid >> 4;

    float acc[4][4] = {};
#pragma unroll 4
    for (int k = 0; k < FIN; ++k) {
        float4 xv = *(const float4*)&Xt[k * 68 + 4 * rg];
        float4 wv = *(const float4*)&Ws[k * 64 + 4 * cg];
#pragma unroll
        for (int i = 0; i < 4; ++i) {
            float xi = (i == 0) ? xv.x : (i == 1) ? xv.y : (i == 2) ? xv.z : xv.w;
            acc[i][0] = fmaf(xi, wv.x, acc[i][0]);
            acc[i][1] = fmaf(xi, wv.y, acc[i][1]);
            acc[i][2] = fmaf(xi, wv.z, acc[i][2]);
            acc[i][3] = fmaf(xi, wv.w, acc[i][3]);
        }
    }

    if (4 * cg + 4 <= FOUT) {
#pragma unroll
        for (int i = 0; i < 4; ++i) {
            int row = r0 + 4 * rg + i;
            if (row < NNODE) {
                float dv = dinv[row];
                ushort4 o = { f2bf(acc[i][0] * dv), f2bf(acc[i][1] * dv),
                              f2bf(acc[i][2] * dv), f2bf(acc[i][3] * dv) };
                *(ushort4*)(XWs + (size_t)row * FOUT + 4 * cg) = o;
            }
        }
    }
}

// ---------------- CSR aggregate + finalize: 2-deep MLP unroll --------------
// EDGE_DINV: XWs rows are RAW -> apply dinv[src] per edge, self needs dinv[d]
// once extra (layer 1). Else rows are prescaled.

template<int F, bool RELU, bool OUTBF, bool EDGE_DINV>
__launch_bounds__(256)
__global__ void k_aggregate(const unsigned short* __restrict__ XWs, const int* __restrict__ rowstart,
                            const unsigned short* __restrict__ csr_src, const float* __restrict__ dinv,
                            const float* __restrict__ b, void* __restrict__ outp) {
    constexpr int NQ = F / 8;
    const int wid  = threadIdx.x >> 6;
    const int lane = threadIdx.x & 63;
    const int g = lane >> 3;
    const int q = lane & 7;
    const int d = blockIdx.x * 4 + wid;
    if (d >= NNODE) return;

    const int beg = rowstart[d];
    const int end = rowstart[d + 1];
    const bool qa = (q < NQ);

    float acc[8] = {};

    for (int base = beg; base < end; base += 64) {
        int idx = base + lane;
        int sv = (idx < end) ? (int)csr_src[idx] : 0;
        int nv = min(64, end - base);
        int nf = nv >> 3;               // full 8-edge rounds
        int k = 0;
        for (; k + 2 <= nf; k += 2) {   // 2 gathers in flight
            int sA = __shfl(sv, 8 * k + g);
            int sB = __shfl(sv, 8 * k + 8 + g);
            if (qa) {
                uint4 vA = *(const uint4*)(XWs + (size_t)sA * F + 8 * q);
                uint4 vB = *(const uint4*)(XWs + (size_t)sB * F + 8 * q);
                float dA = EDGE_DINV ? dinv[sA] : 1.0f;
                float dB = EDGE_DINV ? dinv[sB] : 1.0f;
                if (EDGE_DINV) {
                    acc[0] = fmaf(bfLO(vA.x), dA, acc[0]); acc[1] = fmaf(bfHI(vA.x), dA, acc[1]);
                    acc[2] = fmaf(bfLO(vA.y), dA, acc[2]); acc[3] = fmaf(bfHI(vA.y), dA, acc[3]);
                    acc[4] = fmaf(bfLO(vA.z), dA, acc[4]); acc[5] = fmaf(bfHI(vA.z), dA, acc[5]);
                    acc[6] = fmaf(bfLO(vA.w), dA, acc[6]); acc[7] = fmaf(bfHI(vA.w), dA, acc[7]);
                    acc[0] = fmaf(bfLO(vB.x), dB, acc[0]); acc[1] = fmaf(bfHI(vB.x), dB, acc[1]);
                    acc[2] = fmaf(bfLO(vB.y), dB, acc[2]); acc[3] = fmaf(bfHI(vB.y), dB, acc[3]);
                    acc[4] = fmaf(bfLO(vB.z), dB, acc[4]); acc[5] = fmaf(bfHI(vB.z), dB, acc[5]);
                    acc[6] = fmaf(bfLO(vB.w), dB, acc[6]); acc[7] = fmaf(bfHI(vB.w), dB, acc[7]);
                } else {
                    acc[0] += bfLO(vA.x); acc[1] += bfHI(vA.x);
                    acc[2] += bfLO(vA.y); acc[3] += bfHI(vA.y);
                    acc[4] += bfLO(vA.z); acc[5] += bfHI(vA.z);
                    acc[6] += bfLO(vA.w); acc[7] += bfHI(vA.w);
                    acc[0] += bfLO(vB.x); acc[1] += bfHI(vB.x);
                    acc[2] += bfLO(vB.y); acc[3] += bfHI(vB.y);
                    acc[4] += bfLO(vB.z); acc[5] += bfHI(vB.z);
                    acc[6] += bfLO(vB.w); acc[7] += bfHI(vB.w);
                }
            }
        }
        for (; k < nf; ++k) {
            int s = __shfl(sv, 8 * k + g);
            if (qa) {
                uint4 v = *(const uint4*)(XWs + (size_t)s * F + 8 * q);
                float ds = EDGE_DINV ? dinv[s] : 1.0f;
                if (EDGE_DINV) {
                    acc[0] = fmaf(bfLO(v.x), ds, acc[0]); acc[1] = fmaf(bfHI(v.x), ds, acc[1]);
                    acc[2] = fmaf(bfLO(v.y), ds, acc[2]); acc[3] = fmaf(bfHI(v.y), ds, acc[3]);
                    acc[4] = fmaf(bfLO(v.z), ds, acc[4]); acc[5] = fmaf(bfHI(v.z), ds, acc[5]);
                    acc[6] = fmaf(bfLO(v.w), ds, acc[6]); acc[7] = fmaf(bfHI(v.w), ds, acc[7]);
                } else {
                    acc[0] += bfLO(v.x); acc[1] += bfHI(v.x);
                    acc[2] += bfLO(v.y); acc[3] += bfHI(v.y);
                    acc[4] += bfLO(v.z); acc[5] += bfHI(v.z);
                    acc[6] += bfLO(v.w); acc[7] += bfHI(v.w);
                }
            }
        }
        int rem = nv - (nf << 3);
        if (rem) {
            int jj = (nf << 3) + g;
            int s = __shfl(sv, jj);
            if (g < rem && qa) {
                uint4 v = *(const uint4*)(XWs + (size_t)s * F + 8 * q);
                float ds = EDGE_DINV ? dinv[s] : 1.0f;
                if (EDGE_DINV) {
                    acc[0] = fmaf(bfLO(v.x), ds, acc[0]); acc[1] = fmaf(bfHI(v.x), ds, acc[1]);
                    acc[2] = fmaf(bfLO(v.y), ds, acc[2]); acc[3] = fmaf(bfHI(v.y), ds, acc[3]);
                    acc[4] = fmaf(bfLO(v.z), ds, acc[4]); acc[5] = fmaf(bfHI(v.z), ds, acc[5]);
                    acc[6] = fmaf(bfLO(v.w), ds, acc[6]); acc[7] = fmaf(bfHI(v.w), ds, acc[7]);
                } else {
                    acc[0] += bfLO(v.x); acc[1] += bfHI(v.x);
                    acc[2] += bfLO(v.y); acc[3] += bfHI(v.y);
                    acc[4] += bfLO(v.z); acc[5] += bfHI(v.z);
                    acc[6] += bfLO(v.w); acc[7] += bfHI(v.w);
                }
            }
        }
    }

#pragma unroll
    for (int mask = 8; mask <= 32; mask <<= 1) {
#pragma unroll
        for (int t = 0; t < 8; ++t) acc[t] += __shfl_xor(acc[t], mask);
    }

    if (g == 0 && qa) {
        uint4 sv4 = *(const uint4*)(XWs + (size_t)d * F + 8 * q);
        float self[8] = { bfLO(sv4.x), bfHI(sv4.x), bfLO(sv4.y), bfHI(sv4.y),
                          bfLO(sv4.z), bfHI(sv4.z), bfLO(sv4.w), bfHI(sv4.w) };
        float dv = dinv[d];
        float ss = EDGE_DINV ? dv : 1.0f;
        float o[8];
#pragma unroll
        for (int t = 0; t < 8; ++t) {
            o[t] = fmaf(acc[t] + self[t] * ss, dv, b[8 * q + t]);
            if (RELU) o[t] = fmaxf(o[t], 0.f);
        }
        if (OUTBF) {
            ushort8v ov;
#pragma unroll
            for (int t = 0; t < 8; ++t) ov[t] = f2bf(o[t]);
            *(ushort8v*)((unsigned short*)outp + (size_t)d * F + 8 * q) = ov;
        } else {
            float4 o0 = { o[0], o[1], o[2], o[3] };
            float4 o1 = { o[4], o[5], o[6], o[7] };
            *(float4*)((float*)outp + (size_t)d * F + 8 * q)     = o0;
            *(float4*)((float*)outp + (size_t)d * F + 8 * q + 4) = o1;
        }
    }
}

extern "C" void kernel_launch(void* const* d_in, const int* in_sizes, int n_in,
                              void* d_out, int out_size, void* d_ws, size_t ws_size,
                              hipStream_t stream) {
    const float* x  = (const float*)d_in[0];
    const int*   ei = (const int*)d_in[1];
    const float* W1 = (const float*)d_in[2];
    const float* b1 = (const float*)d_in[3];
    const float* W2 = (const float*)d_in[4];
    const float* b2 = (const float*)d_in[5];
    const float* W3 = (const float*)d_in[6];
    const float* b3 = (const float*)d_in[7];
    float* out = (float*)d_out;

    const int* src = ei;
    const int* dst = ei + NEDGE;

    char* p = (char*)d_ws;
    auto alloc = [&](size_t bytes) { char* r = p; p += (bytes + 255) & ~size_t(255); return r; };
    unsigned int* bucketed = (unsigned int*)alloc((size_t)NEDGE * 4);
    int*   hist_g     = (int*)  alloc(NBUCKET * 256 * 4);
    int*   base_g     = (int*)  alloc(NBUCKET * 256 * 4);
    int*   colsum     = (int*)  alloc(NBUCKET * 4);
    int*   rowstart   = (int*)  alloc((NNODE + 1) * 4);
    unsigned short* csr_src = (unsigned short*)alloc((size_t)NEDGE * 2);
    float* dinvp      = (float*)alloc(NNODE * 4);
    unsigned short* XWs = (unsigned short*)alloc((size_t)NNODE * 64 * 2 + 256);
    unsigned short* H1  = (unsigned short*)alloc((size_t)NNODE * 64 * 2 + 256);
    unsigned short* H2  = (unsigned short*)alloc((size_t)NNODE * 64 * 2 + 256);

    const int B = 256;
    const int gGemm = (NNODE + 63) / 64;          // 782
    const int gAgg  = (NNODE + 3) / 4;            // 12500

    // hist ∥ GEMM1(raw) in one launch, then CSR chain
    k_hist_gemm1<<<256 + G1BLK, B, 0, stream>>>(dst, hist_g, x, W1, XWs);
    k_scanA1  <<<NBUCKET, B, 0, stream>>>(hist_g, base_g, colsum);
    k_scatterA<<<256, B, 0, stream>>>(src, dst, base_g, colsum, bucketed);
    k_bucketB2<<<NBUCKET, B, 0, stream>>>(bucketed, colsum, rowstart, csr_src, dinvp);

    // layer 1 aggregate: raw rows -> per-edge dinv
    k_aggregate<64, true, true, true><<<gAgg, B, 0, stream>>>(XWs, rowstart, csr_src, dinvp, b1, H1);

    // layer 2: 64 -> 64, relu
    k_gemm_prescale<64, 64><<<gGemm, B, 0, stream>>>(H1, W2, dinvp, XWs);
    k_aggregate<64, true, true, false><<<gAgg, B, 0, stream>>>(XWs, rowstart, csr_src, dinvp, b2, H2);

    // layer 3: 64 -> 40, no act, f32 out
    k_gemm_prescale<64, 40><<<gGemm, B, 0, stream>>>(H2, W3, dinvp, XWs);
    k_aggregate<40, false, false, false><<<gAgg, B, 0, stream>>>(XWs, rowstart, csr_src, dinvp, b3, out);
}